// Round 1
// baseline (623.712 us; speedup 1.0000x reference)
//
#include <hip/hip_runtime.h>

#define BB 8
#define CC 256
#define TT 4
#define NNv 4096
#define HH 1024
#define LLv (TT*NNv)   // 16384

typedef short bf16x8 __attribute__((ext_vector_type(8)));
typedef float f32x4 __attribute__((ext_vector_type(4)));

static __device__ __forceinline__ float bfbits2f(unsigned short h) {
    return __uint_as_float(((unsigned int)h) << 16);
}
static __device__ __forceinline__ unsigned short f2bf(float f) {
    unsigned int u = __float_as_uint(f);
    return (unsigned short)((u + 0x7FFFu + ((u >> 16) & 1u)) >> 16);
}
// byte j of a group-of-8 lands at fragment slot p = permpos(j); the spike
// expansion below emits source bytes in order {0,2,4,6,1,3,5,7} at slots 0..7.
static __device__ __forceinline__ int permpos(int j) { return (j >> 1) + ((j & 1) << 2); }

// byte->bf16 {0,1}: slot p holds source byte perm[p], perm = {0,2,4,6,1,3,5,7}
static __device__ __forceinline__ uint4 spikes8_to_bf16(unsigned long long d) {
    unsigned int lo = (unsigned int)d, hi = (unsigned int)(d >> 32);
    uint4 o;
    o.x = (lo & 0x10001u) * 0x3F80u;
    o.y = (hi & 0x10001u) * 0x3F80u;
    o.z = ((lo >> 8) & 0x10001u) * 0x3F80u;
    o.w = ((hi >> 8) & 0x10001u) * 0x3F80u;
    return o;
}

// ---- fc1 weights -> fragment-linear 3-split (hi/mid/lo), k-permuted ----
// dst: ((((ht*4+ko)*2+kb)*4+g)*64 + q*16+ln)*8 + p   (+ s*262144)
__global__ __launch_bounds__(256) void k_prep1(const float* __restrict__ w,
                                               unsigned short* __restrict__ wf)
{
    int i = blockIdx.x * 256 + threadIdx.x;        // i = h*256 + c
    int h = i >> 8, c = i & 255;
    int ht = h >> 6, hr = h & 63, g = hr >> 4, ln = hr & 15;
    int ko = c >> 6, cr = c & 63, kb = cr >> 5, q = (cr >> 3) & 3, j = c & 7;
    size_t base = (((((size_t)ht * 4 + ko) * 2 + kb) * 4 + g) * 64 + q * 16 + ln) * 8 + permpos(j);
    const size_t WS = 262144;
    float x = w[i];
    unsigned short hi = f2bf(x); float r  = __fsub_rn(x, bfbits2f(hi));
    unsigned short md = f2bf(r); float r2 = __fsub_rn(r, bfbits2f(md));
    unsigned short lo = f2bf(r2);
    wf[base] = hi; wf[WS + base] = md; wf[2 * WS + base] = lo;
}

// ---- fc2 weights -> fragment-linear 2-split (hi/lo), k-permuted ----
// dst: ((((ct*8+ko)*4+kb)*4+g)*64 + q*16+ln)*8 + p   (+ s*262144)
__global__ __launch_bounds__(256) void k_prep2(const float* __restrict__ w,
                                               unsigned short* __restrict__ wf)
{
    int i = blockIdx.x * 256 + threadIdx.x;        // i = c*1024 + h
    int c = i >> 10, h = i & 1023;
    int ct = c >> 6, cr = c & 63, g = cr >> 4, ln = cr & 15;
    int ko = h >> 7, hr = h & 127, kb = hr >> 5, q = (hr >> 3) & 3, j = h & 7;
    size_t base = (((((size_t)ct * 8 + ko) * 4 + kb) * 4 + g) * 64 + q * 16 + ln) * 8 + permpos(j);
    const size_t WS = 262144;
    float x = w[i];
    unsigned short hi = f2bf(x); float r = __fsub_rn(x, bfbits2f(hi));
    unsigned short lo = f2bf(r);
    wf[base] = hi; wf[WS + base] = lo;
}

// ---- bn2 + LIF over T + transpose: x[b][c][t][n] -> s1T[bl][t][n][c] bytes ----
// b0: global batch offset for x; s1T is indexed by chunk-local bl = blockIdx.z
__global__ __launch_bounds__(256) void k_bn2_lif_t(
    const float* __restrict__ x,
    const float* __restrict__ g, const float* __restrict__ be,
    const float* __restrict__ mu, const float* __restrict__ va,
    unsigned char* __restrict__ s1T, int b0)
{
    __shared__ unsigned char ts[TT][64][80];       // [t][c][n], stride 80 (16B-aligned)
    int tx = threadIdx.x;
    int n0 = blockIdx.x * 64;
    int c0 = blockIdx.y * 64;
    int bl = blockIdx.z;
    int b  = b0 + bl;
    int cl = tx >> 2, np = tx & 3;
    int c = c0 + cl;
    float rsq = __fdiv_rn(1.0f, __fsqrt_rn(__fadd_rn(va[c], 1e-5f)));
    float inv = __fmul_rn(g[c], rsq);
    float add = __fsub_rn(be[c], __fmul_rn(mu[c], inv));
    size_t xb = ((size_t)(b * CC + c) * TT) * NNv + n0 + np * 16;
    float v[16];
    #pragma unroll
    for (int i = 0; i < 16; i++) v[i] = 0.0f;
    #pragma unroll
    for (int t = 0; t < TT; t++) {
        float4 p[4];
        #pragma unroll
        for (int k = 0; k < 4; k++) p[k] = *(const float4*)(x + xb + (size_t)t * NNv + 4 * k);
        const float* xp = (const float*)p;
        unsigned int ob[4] = {0, 0, 0, 0};
        #pragma unroll
        for (int i = 0; i < 16; i++) {
            float y = __fadd_rn(__fmul_rn(xp[i], inv), add);
            float vv = __fadd_rn(v[i], __fdiv_rn(__fsub_rn(y, v[i]), 1.5f));
            bool sp = vv >= 1.0f;
            v[i] = sp ? 0.0f : vv;
            if (sp) ob[i >> 2] |= 1u << (8 * (i & 3));
        }
        uint4 pk; pk.x = ob[0]; pk.y = ob[1]; pk.z = ob[2]; pk.w = ob[3];
        *(uint4*)&ts[t][cl][np * 16] = pk;
    }
    __syncthreads();
    int nl = tx >> 2, cp = tx & 3;
    #pragma unroll
    for (int t = 0; t < TT; t++) {
        unsigned int u[4];
        #pragma unroll
        for (int kk = 0; kk < 4; kk++) {
            u[kk] = (unsigned int)ts[t][cp * 16 + kk * 4 + 0][nl]
                  | ((unsigned int)ts[t][cp * 16 + kk * 4 + 1][nl] << 8)
                  | ((unsigned int)ts[t][cp * 16 + kk * 4 + 2][nl] << 16)
                  | ((unsigned int)ts[t][cp * 16 + kk * 4 + 3][nl] << 24);
        }
        uint4 pk; pk.x = u[0]; pk.y = u[1]; pk.z = u[2]; pk.w = u[3];
        *(uint4*)(s1T + ((size_t)(bl * TT + t) * NNv + n0 + nl) * CC + c0 + cp * 16) = pk;
    }
}

// ------- GEMM1 (fc1) 3-split, W-frags from global, spikes-only LDS, fused bn1+LIF -------
// s1T and s2T are chunk-local (host pre-offsets the s1T pointer); bl = blockIdx.z
__global__ __launch_bounds__(256) void k_gemm1_lif(
    const unsigned short* __restrict__ w1f,
    const float* __restrict__ b1,
    const float* __restrict__ g1, const float* __restrict__ be1,
    const float* __restrict__ mu1, const float* __restrict__ va1,
    const unsigned char* __restrict__ s1T, unsigned char* __restrict__ s2T)
{
    __shared__ unsigned short Ss[TT][64][72];
    const int tx = threadIdx.x;
    const int n0 = blockIdx.x * 64;
    const int ht = blockIdx.y;
    const int bl = blockIdx.z;
    const int lane = tx & 63, w = tx >> 6;
    const int q = lane >> 4, ln = lane & 15;
    const int mh = (w & 1) * 32, wn = (w >> 1) * 32;
    const int h0 = ht * 64;
    const size_t WS = 262144;

    f32x4 acc[TT][2][2];
    #pragma unroll
    for (int t = 0; t < TT; t++)
    #pragma unroll
    for (int mi = 0; mi < 2; mi++)
    #pragma unroll
    for (int ni = 0; ni < 2; ni++)
        acc[t][mi][ni] = (f32x4){0.f, 0.f, 0.f, 0.f};

    for (int ko = 0; ko < 4; ko++) {
        __syncthreads();
        #pragma unroll
        for (int i = 0; i < 8; i++) {
            int task = i * 256 + tx;
            int cb = task & 7, nr = (task >> 3) & 63, t = task >> 9;
            unsigned long long d = *(const unsigned long long*)(
                s1T + ((size_t)(bl * TT + t) * NNv + n0 + nr) * CC + ko * 64 + cb * 8);
            *(uint4*)&Ss[t][nr][cb * 8] = spikes8_to_bf16(d);
        }
        __syncthreads();
        #pragma unroll
        for (int kb = 0; kb < 2; kb++) {
            bf16x8 wf[2][3];
            #pragma unroll
            for (int mi = 0; mi < 2; mi++) {
                int gg = (mh >> 4) + mi;
                size_t fbase = (((((size_t)ht * 4 + ko) * 2 + kb) * 4 + gg) * 64 + lane) * 8;
                #pragma unroll
                for (int s = 0; s < 3; s++)
                    wf[mi][s] = *(const bf16x8*)(w1f + s * WS + fbase);
            }
            #pragma unroll
            for (int t = 0; t < TT; t++) {
                bf16x8 sf0 = *(const bf16x8*)&Ss[t][wn + ln][kb * 32 + q * 8];
                bf16x8 sf1 = *(const bf16x8*)&Ss[t][wn + 16 + ln][kb * 32 + q * 8];
                #pragma unroll
                for (int s = 0; s < 3; s++) {
                    acc[t][0][0] = __builtin_amdgcn_mfma_f32_16x16x32_bf16(wf[0][s], sf0, acc[t][0][0], 0, 0, 0);
                    acc[t][0][1] = __builtin_amdgcn_mfma_f32_16x16x32_bf16(wf[0][s], sf1, acc[t][0][1], 0, 0, 0);
                    acc[t][1][0] = __builtin_amdgcn_mfma_f32_16x16x32_bf16(wf[1][s], sf0, acc[t][1][0], 0, 0, 0);
                    acc[t][1][1] = __builtin_amdgcn_mfma_f32_16x16x32_bf16(wf[1][s], sf1, acc[t][1][1], 0, 0, 0);
                }
            }
        }
    }

    // epilogue: bias + bn1 + LIF scan over t; packed 4-byte spike stores to s2T[bl][l][h]
    #pragma unroll
    for (int mi = 0; mi < 2; mi++) {
        float invr[4], addr_[4], biasr[4];
        #pragma unroll
        for (int r = 0; r < 4; r++) {
            int h = h0 + mh + mi * 16 + q * 4 + r;
            float rsq = __fdiv_rn(1.0f, __fsqrt_rn(__fadd_rn(va1[h], 1e-5f)));
            invr[r] = __fmul_rn(g1[h], rsq);
            addr_[r] = __fsub_rn(be1[h], __fmul_rn(mu1[h], invr[r]));
            biasr[r] = b1[h];
        }
        #pragma unroll
        for (int ni = 0; ni < 2; ni++) {
            int l_n = n0 + wn + ni * 16 + ln;
            float v4[4] = {0.f, 0.f, 0.f, 0.f};
            #pragma unroll
            for (int t = 0; t < TT; t++) {
                unsigned int pk = 0;
                #pragma unroll
                for (int r = 0; r < 4; r++) {
                    float h1 = __fadd_rn(acc[t][mi][ni][r], biasr[r]);
                    float y  = __fadd_rn(__fmul_rn(h1, invr[r]), addr_[r]);
                    float vv = __fadd_rn(v4[r], __fdiv_rn(__fsub_rn(y, v4[r]), 1.5f));
                    bool sp = vv >= 1.0f;
                    v4[r] = sp ? 0.0f : vv;
                    if (sp) pk |= (1u << (8 * r));
                }
                *(unsigned int*)(s2T + ((size_t)bl * LLv + t * NNv + l_n) * HH
                                 + h0 + mh + mi * 16 + q * 4) = pk;
            }
        }
    }
}

// ------- GEMM2 (fc2) 2-split, W-frags from global, spikes-only LDS, fp32 out -------
// s2T chunk-local (bl = blockIdx.z); outp global via b = b0 + bl
__global__ __launch_bounds__(256) void k_gemm2(
    const unsigned short* __restrict__ w2f,
    const float* __restrict__ b2c,
    const unsigned char* __restrict__ s2T, float* __restrict__ outp, int b0)
{
    __shared__ unsigned short Ss[128][136];
    const int tx = threadIdx.x;
    const int l0 = blockIdx.x * 128;
    const int ct = blockIdx.y;
    const int bl = blockIdx.z;
    const int b  = b0 + bl;
    const int lane = tx & 63, w = tx >> 6;
    const int q = lane >> 4, ln = lane & 15;
    const int mc = (w & 1) * 32, wl = (w >> 1) * 64;
    const size_t WS = 262144;

    f32x4 acc[2][4];
    #pragma unroll
    for (int mi = 0; mi < 2; mi++)
    #pragma unroll
    for (int ni = 0; ni < 4; ni++)
        acc[mi][ni] = (f32x4){0.f, 0.f, 0.f, 0.f};

    for (int ko = 0; ko < 8; ko++) {
        __syncthreads();
        #pragma unroll
        for (int i = 0; i < 8; i++) {
            int task = i * 256 + tx;
            int hb = task & 15, lr = task >> 4;
            unsigned long long d = *(const unsigned long long*)(
                s2T + ((size_t)bl * LLv + l0 + lr) * HH + ko * 128 + hb * 8);
            *(uint4*)&Ss[lr][hb * 8] = spikes8_to_bf16(d);
        }
        __syncthreads();
        #pragma unroll
        for (int kb = 0; kb < 4; kb++) {
            bf16x8 wf[2][2];
            #pragma unroll
            for (int mi = 0; mi < 2; mi++) {
                int gg = (mc >> 4) + mi;
                size_t fbase = (((((size_t)ct * 8 + ko) * 4 + kb) * 4 + gg) * 64 + lane) * 8;
                #pragma unroll
                for (int s = 0; s < 2; s++)
                    wf[mi][s] = *(const bf16x8*)(w2f + s * WS + fbase);
            }
            bf16x8 sf[4];
            #pragma unroll
            for (int ni = 0; ni < 4; ni++)
                sf[ni] = *(const bf16x8*)&Ss[wl + ni * 16 + ln][kb * 32 + q * 8];
            #pragma unroll
            for (int s = 0; s < 2; s++)
            #pragma unroll
            for (int mi = 0; mi < 2; mi++)
            #pragma unroll
            for (int ni = 0; ni < 4; ni++)
                acc[mi][ni] = __builtin_amdgcn_mfma_f32_16x16x32_bf16(wf[mi][s], sf[ni], acc[mi][ni], 0, 0, 0);
        }
    }
    #pragma unroll
    for (int mi = 0; mi < 2; mi++)
    #pragma unroll
    for (int r = 0; r < 4; r++) {
        int c = ct * 64 + mc + mi * 16 + q * 4 + r;
        float bias = b2c[c];
        #pragma unroll
        for (int ni = 0; ni < 4; ni++) {
            int l = l0 + wl + ni * 16 + ln;
            outp[((size_t)b * CC + c) * LLv + l] = __fadd_rn(acc[mi][ni][r], bias);
        }
    }
}

extern "C" void kernel_launch(void* const* d_in, const int* in_sizes, int n_in,
                              void* d_out, int out_size, void* d_ws, size_t ws_size,
                              hipStream_t stream) {
    const float* x    = (const float*)d_in[0];
    const float* fc1w = (const float*)d_in[1];
    const float* fc1b = (const float*)d_in[2];
    const float* fc2w = (const float*)d_in[3];
    const float* fc2b = (const float*)d_in[4];
    const float* g1   = (const float*)d_in[5];
    const float* be1  = (const float*)d_in[6];
    const float* mu1  = (const float*)d_in[7];
    const float* va1  = (const float*)d_in[8];
    const float* g2   = (const float*)d_in[9];
    const float* be2  = (const float*)d_in[10];
    const float* mu2  = (const float*)d_in[11];
    const float* va2  = (const float*)d_in[12];

    // Workspace layout (ws_size-adaptive; never exceed ws_size — a previous
    // revision assumed 170.4 MB unconditionally and the s2T tail clobbered an
    // adjacent input allocation, corrupting x from the 2nd call onward):
    //   w1f: 3*262144 shorts (1.5 MB)   fc1 weight fragments
    //   w2f: 2*262144 shorts (1.0 MB)   fc2 weight fragments
    //   s1T: (full? 8 : 1) * 4 MB       bn2+LIF spike bytes [b][t][n][c]
    //   s2T: nbc * 16.78 MB             layer-1 spike bytes [bl][l][h]
    const size_t WB  = (size_t)(3 + 2) * 262144 * sizeof(unsigned short); // 2,621,440
    const size_t S1B = (size_t)TT * NNv * CC;                             // 4,194,304 per b
    const size_t S2B = (size_t)LLv * HH;                                  // 16,777,216 per b

    int nbc;          // batch elements per gemm1/gemm2 chunk
    bool full_s1;     // s1T holds all 8 batches (bn2 runs once)?
    if      (ws_size >= WB + 8 * S1B + 8 * S2B) { nbc = 8; full_s1 = true;  }
    else if (ws_size >= WB + 8 * S1B + 4 * S2B) { nbc = 4; full_s1 = true;  }
    else if (ws_size >= WB + 8 * S1B + 2 * S2B) { nbc = 2; full_s1 = true;  }
    else if (ws_size >= WB + 8 * S1B + 1 * S2B) { nbc = 1; full_s1 = true;  }
    else                                        { nbc = 1; full_s1 = false; }

    unsigned short* w1f = (unsigned short*)d_ws;                        // 3*262144 shorts
    unsigned short* w2f = w1f + (size_t)3 * 262144;                     // 2*262144 shorts
    unsigned char*  s1T = (unsigned char*)(w2f + (size_t)2 * 262144);
    unsigned char*  s2T = s1T + (full_s1 ? (size_t)8 * S1B : S1B);
    float* outp = (float*)d_out;

    hipLaunchKernelGGL(k_prep1, dim3(1024), dim3(256), 0, stream, fc1w, w1f);
    hipLaunchKernelGGL(k_prep2, dim3(1024), dim3(256), 0, stream, fc2w, w2f);

    if (full_s1) {
        hipLaunchKernelGGL(k_bn2_lif_t, dim3(NNv / 64, CC / 64, BB), dim3(256), 0, stream,
                           x, g2, be2, mu2, va2, s1T, 0);
        for (int b0 = 0; b0 < BB; b0 += nbc) {
            hipLaunchKernelGGL(k_gemm1_lif, dim3(NNv / 64, HH / 64, nbc), dim3(256), 0, stream,
                               w1f, fc1b, g1, be1, mu1, va1, s1T + (size_t)b0 * S1B, s2T);
            hipLaunchKernelGGL(k_gemm2, dim3(LLv / 128, CC / 64, nbc), dim3(256), 0, stream,
                               w2f, fc2b, s2T, outp, b0);
        }
    } else {
        for (int b0 = 0; b0 < BB; ++b0) {
            hipLaunchKernelGGL(k_bn2_lif_t, dim3(NNv / 64, CC / 64, 1), dim3(256), 0, stream,
                               x, g2, be2, mu2, va2, s1T, b0);
            hipLaunchKernelGGL(k_gemm1_lif, dim3(NNv / 64, HH / 64, 1), dim3(256), 0, stream,
                               w1f, fc1b, g1, be1, mu1, va1, s1T, s2T);
            hipLaunchKernelGGL(k_gemm2, dim3(LLv / 128, CC / 64, 1), dim3(256), 0, stream,
                               w2f, fc2b, s2T, outp, b0);
        }
    }
}